// Round 4
// baseline (945.653 us; speedup 1.0000x reference)
//
#include <hip/hip_runtime.h>

#define NN 100000
#define NE 1000000
#define NBK 391          // coarse buckets of 256 nodes: (NN+255)/256
#define CH 8192          // edges per binning block
#define NCB ((NE + CH - 1) / CH)   // 123

typedef __attribute__((ext_vector_type(8))) short bf16x8;
typedef __attribute__((ext_vector_type(4))) float f32x4;

// ---------------------------------------------------------------------------
// bf16 helpers (RNE)
__device__ __forceinline__ ushort f2bf(float f) {
    uint u = __builtin_bit_cast(uint, f);
    u += 0x7FFFu + ((u >> 16) & 1u);
    return (ushort)(u >> 16);
}
__device__ __forceinline__ uint pack2(float a, float b) {
    uint ua = __builtin_bit_cast(uint, a), ub = __builtin_bit_cast(uint, b);
    ua += 0x7FFFu + ((ua >> 16) & 1u);
    ub += 0x7FFFu + ((ub >> 16) & 1u);
    return (ua >> 16) | (ub & 0xFFFF0000u);
}
__device__ __forceinline__ float blo(uint v) { return __builtin_bit_cast(float, v << 16); }
__device__ __forceinline__ float bhi(uint v) { return __builtin_bit_cast(float, v & 0xFFFF0000u); }

// ---------------------------------------------------------------------------
__global__ void cvt_x(const float* __restrict__ x, uint* __restrict__ xb2) {
    int t = blockIdx.x * blockDim.x + threadIdx.x;   // one float4 per thread
    if (t < NN * 16) {
        float4 v = reinterpret_cast<const float4*>(x)[t];
        uint2 o;
        o.x = pack2(v.x, v.y);
        o.y = pack2(v.z, v.w);
        reinterpret_cast<uint2*>(xb2)[t] = o;
    }
}

// W1t[f][k] (64x128): k<64 -> W1l[k][f], else W1r[k-64][f];  W2t (32x128) same.
__global__ void prep_w(const float* __restrict__ W1l, const float* __restrict__ W1r,
                       const float* __restrict__ W2l, const float* __restrict__ W2r,
                       ushort* __restrict__ W1t, ushort* __restrict__ W2t) {
    int t = blockIdx.x * blockDim.x + threadIdx.x;
    if (t < 64 * 128) {
        int f = t >> 7, k = t & 127;
        float v = (k < 64) ? W1l[k * 64 + f] : W1r[(k - 64) * 64 + f];
        W1t[t] = f2bf(v);
    } else if (t < 64 * 128 + 32 * 128) {
        int u = t - 64 * 128;
        int f = u >> 7, k = u & 127;
        float v = (k < 64) ? W2l[k * 32 + f] : W2r[(k - 64) * 32 + f];
        W2t[u] = f2bf(v);
    }
}

// ---------------------------------------------------------------------------
// Coarse histogram over buckets (dst >> 8), LDS-staged.
__global__ __launch_bounds__(512) void coarse_hist(const int* __restrict__ dst,
                                                   int* __restrict__ gh) {
    __shared__ int lh[NBK + 1];
    int tid = threadIdx.x;
    for (int i = tid; i < NBK + 1; i += 512) lh[i] = 0;
    __syncthreads();
    int base = blockIdx.x * CH;
#pragma unroll
    for (int k = 0; k < 16; ++k) {
        int e = base + tid + k * 512;
        if (e < NE) atomicAdd(&lh[dst[e] >> 8], 1);
    }
    __syncthreads();
    if (tid < NBK && lh[tid] > 0) atomicAdd(&gh[tid], lh[tid]);
}

// Exclusive scan of 391 bucket counts (Hillis-Steele over 512).
__global__ __launch_bounds__(512) void scan_buckets(const int* __restrict__ gh,
                                                    int* __restrict__ goff,
                                                    int* __restrict__ gcur) {
    __shared__ int s[512];
    int t = threadIdx.x;
    int v = (t < NBK) ? gh[t] : 0;
    s[t] = v;
    for (int d = 1; d < 512; d <<= 1) {
        __syncthreads();
        int add = (t >= d) ? s[t - d] : 0;
        __syncthreads();
        s[t] += add;
    }
    __syncthreads();
    int ex = s[t] - v;
    if (t < NBK) { goff[t] = ex; gcur[t] = ex; }
    if (t == NBK - 1) goff[NBK] = ex + v;   // == NE
}

// Binned scatter: per block, reserve contiguous runs per bucket, write packed
// records src | (dstLocal << 24). Runs ~21 edges -> ~84B contiguous writes.
__global__ __launch_bounds__(512) void bin_edges(const int* __restrict__ src,
                                                 const int* __restrict__ dst,
                                                 int* __restrict__ gcur,
                                                 uint* __restrict__ binned) {
    __shared__ int lh[NBK + 1], lb[NBK + 1], lr[NBK + 1];
    int tid = threadIdx.x;
    for (int i = tid; i < NBK + 1; i += 512) { lh[i] = 0; lr[i] = 0; }
    __syncthreads();
    int base = blockIdx.x * CH;
#pragma unroll
    for (int k = 0; k < 16; ++k) {
        int e = base + tid + k * 512;
        if (e < NE) atomicAdd(&lh[dst[e] >> 8], 1);
    }
    __syncthreads();
    if (tid < NBK && lh[tid] > 0) lb[tid] = atomicAdd(&gcur[tid], lh[tid]);
    __syncthreads();
#pragma unroll
    for (int k = 0; k < 16; ++k) {
        int e = base + tid + k * 512;
        if (e < NE) {
            int d = dst[e];
            int bk = d >> 8;
            int r = atomicAdd(&lr[bk], 1);
            binned[lb[bk] + r] = (uint)src[e] | ((uint)(d & 255) << 24);
        }
    }
}

// ---------------------------------------------------------------------------
// Aggregate mean per bucket: LDS fp32 accumulator [256 nodes][64 feats],
// pair-interleaved (slot c = feat 2c, slot 32+c = feat 2c+1) so both
// ds_add_f32 of a half-wave hit 32 distinct banks (2-way across halves = free).
// 32 half-waves x unroll 2 = 64 row-gathers in flight per block.
__global__ __launch_bounds__(1024) void agg_mean(const uint* __restrict__ rows,
                                                 const uint* __restrict__ binned,
                                                 const int* __restrict__ goff,
                                                 uint* __restrict__ mout) {
    __shared__ float acc[256 * 64];
    __shared__ int sdeg[256];
    int tid = threadIdx.x;
    for (int i = tid; i < 256 * 16; i += 1024)
        reinterpret_cast<float4*>(acc)[i] = float4{0.f, 0.f, 0.f, 0.f};
    if (tid < 256) sdeg[tid] = 0;
    __syncthreads();
    int b = blockIdx.x;
    int s = goff[b], e = goff[b + 1];
    int H = tid >> 5, c = tid & 31;
    int i = s + H;
    for (; i + 32 < e; i += 64) {
        uint r0 = binned[i], r1 = binned[i + 32];
        uint v0 = rows[(size_t)(r0 & 0xFFFFFFu) * 32 + c];
        uint v1 = rows[(size_t)(r1 & 0xFFFFFFu) * 32 + c];
        int d0 = r0 >> 24, d1 = r1 >> 24;
        atomicAdd(&acc[d0 * 64 + c], blo(v0));
        atomicAdd(&acc[d0 * 64 + 32 + c], bhi(v0));
        atomicAdd(&acc[d1 * 64 + c], blo(v1));
        atomicAdd(&acc[d1 * 64 + 32 + c], bhi(v1));
        if (c == 0) { atomicAdd(&sdeg[d0], 1); atomicAdd(&sdeg[d1], 1); }
    }
    if (i < e) {
        uint r0 = binned[i];
        uint v0 = rows[(size_t)(r0 & 0xFFFFFFu) * 32 + c];
        int d0 = r0 >> 24;
        atomicAdd(&acc[d0 * 64 + c], blo(v0));
        atomicAdd(&acc[d0 * 64 + 32 + c], bhi(v0));
        if (c == 0) atomicAdd(&sdeg[d0], 1);
    }
    __syncthreads();
    int nodeBase = b * 256;
    for (int idx = tid; idx < 256 * 32; idx += 1024) {
        int n = idx >> 5, k = idx & 31;
        int node = nodeBase + n;
        if (node < NN) {
            float invc = 1.f / fmaxf((float)sdeg[n], 1.f);
            mout[(size_t)node * 32 + k] =
                pack2(acc[n * 64 + k] * invc, acc[n * 64 + 32 + k] * invc);
        }
    }
}

// ---------------------------------------------------------------------------
// Layer 1 MFMA: hb = relu(l2norm([mean|x] @ W1t^T + b1)), bf16 out.
// C layout: col = lane&15, row = (lane>>4)*4 + reg  [m89-verified].
__global__ __launch_bounds__(256) void layer1_mfma(
    const ushort* __restrict__ mb, const ushort* __restrict__ xb,
    const ushort* __restrict__ Wt, const float* __restrict__ bias,
    ushort* __restrict__ hb) {
    int w = threadIdx.x >> 6, l = threadIdx.x & 63;
    int r = l & 15, q = l >> 4;
    int node0 = blockIdx.x * 64 + w * 16;
    int arow = node0 + r;
    if (arow >= NN) arow = NN - 1;      // clamp; invalid rows never stored
    const ushort* am = mb + (size_t)arow * 64 + q * 8;
    const ushort* ax = xb + (size_t)arow * 64 + q * 8;
    bf16x8 afr[4];
    afr[0] = *reinterpret_cast<const bf16x8*>(am);
    afr[1] = *reinterpret_cast<const bf16x8*>(am + 32);
    afr[2] = *reinterpret_cast<const bf16x8*>(ax);
    afr[3] = *reinterpret_cast<const bf16x8*>(ax + 32);

    f32x4 c0 = {0.f, 0.f, 0.f, 0.f}, c1 = c0, c2 = c0, c3 = c0;
    const ushort* wp = Wt + (size_t)r * 128 + q * 8;
#pragma unroll
    for (int ks = 0; ks < 4; ++ks) {
        const ushort* wk = wp + ks * 32;
        bf16x8 b0 = *reinterpret_cast<const bf16x8*>(wk);
        bf16x8 b1 = *reinterpret_cast<const bf16x8*>(wk + 16 * 128);
        bf16x8 b2 = *reinterpret_cast<const bf16x8*>(wk + 32 * 128);
        bf16x8 b3 = *reinterpret_cast<const bf16x8*>(wk + 48 * 128);
        c0 = __builtin_amdgcn_mfma_f32_16x16x32_bf16(afr[ks], b0, c0, 0, 0, 0);
        c1 = __builtin_amdgcn_mfma_f32_16x16x32_bf16(afr[ks], b1, c1, 0, 0, 0);
        c2 = __builtin_amdgcn_mfma_f32_16x16x32_bf16(afr[ks], b2, c2, 0, 0, 0);
        c3 = __builtin_amdgcn_mfma_f32_16x16x32_bf16(afr[ks], b3, c3, 0, 0, 0);
    }
    float bb0 = bias[r], bb1 = bias[16 + r], bb2 = bias[32 + r], bb3 = bias[48 + r];
#pragma unroll
    for (int reg = 0; reg < 4; ++reg) {
        c0[reg] += bb0; c1[reg] += bb1; c2[reg] += bb2; c3[reg] += bb3;
    }
    float sc[4];
#pragma unroll
    for (int reg = 0; reg < 4; ++reg) {
        float s = c0[reg] * c0[reg] + c1[reg] * c1[reg] +
                  c2[reg] * c2[reg] + c3[reg] * c3[reg];
        s += __shfl_xor(s, 1, 64);
        s += __shfl_xor(s, 2, 64);
        s += __shfl_xor(s, 4, 64);
        s += __shfl_xor(s, 8, 64);
        sc[reg] = 1.f / fmaxf(sqrtf(s), 1e-12f);
    }
#pragma unroll
    for (int reg = 0; reg < 4; ++reg) {
        int grow = node0 + q * 4 + reg;
        if (grow < NN) {
            ushort* hp = hb + (size_t)grow * 64 + r;
            hp[0]  = f2bf(fmaxf(c0[reg] * sc[reg], 0.f));
            hp[16] = f2bf(fmaxf(c1[reg] * sc[reg], 0.f));
            hp[32] = f2bf(fmaxf(c2[reg] * sc[reg], 0.f));
            hp[48] = f2bf(fmaxf(c3[reg] * sc[reg], 0.f));
        }
    }
}

// Layer 2 MFMA: out = l2norm([mean2|h] @ W2t^T + b2), fp32 out, 32 feats.
__global__ __launch_bounds__(256) void layer2_mfma(
    const ushort* __restrict__ mb, const ushort* __restrict__ hbuf,
    const ushort* __restrict__ Wt, const float* __restrict__ bias,
    float* __restrict__ out) {
    int w = threadIdx.x >> 6, l = threadIdx.x & 63;
    int r = l & 15, q = l >> 4;
    int node0 = blockIdx.x * 64 + w * 16;
    int arow = node0 + r;
    if (arow >= NN) arow = NN - 1;
    const ushort* am = mb + (size_t)arow * 64 + q * 8;
    const ushort* ax = hbuf + (size_t)arow * 64 + q * 8;
    bf16x8 afr[4];
    afr[0] = *reinterpret_cast<const bf16x8*>(am);
    afr[1] = *reinterpret_cast<const bf16x8*>(am + 32);
    afr[2] = *reinterpret_cast<const bf16x8*>(ax);
    afr[3] = *reinterpret_cast<const bf16x8*>(ax + 32);

    f32x4 c0 = {0.f, 0.f, 0.f, 0.f}, c1 = c0;
    const ushort* wp = Wt + (size_t)r * 128 + q * 8;
#pragma unroll
    for (int ks = 0; ks < 4; ++ks) {
        const ushort* wk = wp + ks * 32;
        bf16x8 b0 = *reinterpret_cast<const bf16x8*>(wk);
        bf16x8 b1 = *reinterpret_cast<const bf16x8*>(wk + 16 * 128);
        c0 = __builtin_amdgcn_mfma_f32_16x16x32_bf16(afr[ks], b0, c0, 0, 0, 0);
        c1 = __builtin_amdgcn_mfma_f32_16x16x32_bf16(afr[ks], b1, c1, 0, 0, 0);
    }
    float bb0 = bias[r], bb1 = bias[16 + r];
#pragma unroll
    for (int reg = 0; reg < 4; ++reg) { c0[reg] += bb0; c1[reg] += bb1; }
    float sc[4];
#pragma unroll
    for (int reg = 0; reg < 4; ++reg) {
        float s = c0[reg] * c0[reg] + c1[reg] * c1[reg];
        s += __shfl_xor(s, 1, 64);
        s += __shfl_xor(s, 2, 64);
        s += __shfl_xor(s, 4, 64);
        s += __shfl_xor(s, 8, 64);
        sc[reg] = 1.f / fmaxf(sqrtf(s), 1e-12f);
    }
#pragma unroll
    for (int reg = 0; reg < 4; ++reg) {
        int grow = node0 + q * 4 + reg;
        if (grow < NN) {
            float* op = out + (size_t)grow * 32 + r;
            op[0]  = c0[reg] * sc[reg];
            op[16] = c1[reg] * sc[reg];
        }
    }
}

// ---------------------------------------------------------------------------
extern "C" void kernel_launch(void* const* d_in, const int* in_sizes, int n_in,
                              void* d_out, int out_size, void* d_ws, size_t ws_size,
                              hipStream_t stream) {
    const float* x   = (const float*)d_in[0];
    const int*   ei  = (const int*)d_in[1];
    const int*   src = ei;            // edge_index[0]
    const int*   dst = ei + NE;       // edge_index[1]
    const float* W1l = (const float*)d_in[2];
    const float* b1  = (const float*)d_in[3];
    const float* W1r = (const float*)d_in[4];
    const float* W2l = (const float*)d_in[5];
    const float* b2  = (const float*)d_in[6];
    const float* W2r = (const float*)d_in[7];
    float* out = (float*)d_out;

    // ws: xb | mb | hb (bf16 N*64 each) | W1t | W2t | gh | goff | gcur | binned
    ushort* xb   = (ushort*)d_ws;
    ushort* mb   = xb + (size_t)NN * 64;
    ushort* hb   = mb + (size_t)NN * 64;
    ushort* W1t  = hb + (size_t)NN * 64;
    ushort* W2t  = W1t + 64 * 128;
    int*    gh   = (int*)(W2t + 32 * 128);
    int*    goff = gh + NBK + 1;
    int*    gcur = goff + NBK + 1;
    uint*   binn = (uint*)(gcur + NBK + 1);

    hipMemsetAsync(gh, 0, (NBK + 1) * sizeof(int), stream);

    cvt_x      <<<(NN * 16 + 255) / 256, 256, 0, stream>>>(x, (uint*)xb);
    prep_w     <<<48, 256, 0, stream>>>(W1l, W1r, W2l, W2r, W1t, W2t);
    coarse_hist<<<NCB, 512, 0, stream>>>(dst, gh);
    scan_buckets<<<1, 512, 0, stream>>>(gh, goff, gcur);
    bin_edges  <<<NCB, 512, 0, stream>>>(src, dst, gcur, binn);

    agg_mean   <<<NBK, 1024, 0, stream>>>((const uint*)xb, binn, goff, (uint*)mb);
    layer1_mfma<<<(NN + 63) / 64, 256, 0, stream>>>(mb, xb, W1t, b1, hb);
    agg_mean   <<<NBK, 1024, 0, stream>>>((const uint*)hb, binn, goff, (uint*)mb);
    layer2_mfma<<<(NN + 63) / 64, 256, 0, stream>>>(mb, hb, W2t, b2, out);
}

// Round 5
// 129.070 us; speedup vs baseline: 7.3267x; 7.3267x over previous
//
#include <hip/hip_runtime.h>

#define NN 100000
#define NE 1000000
#define NBK 391          // coarse buckets of 256 nodes
#define CH 8192          // edges per binning block
#define NCB ((NE + CH - 1) / CH)   // 123
#define SCAP 4096        // per-bucket sort capacity (avg 2560, sigma 51)

typedef __attribute__((ext_vector_type(8))) short bf16x8;
typedef __attribute__((ext_vector_type(4))) float f32x4;

// ---------------------------------------------------------------------------
// bf16 helpers (RNE)
__device__ __forceinline__ ushort f2bf(float f) {
    uint u = __builtin_bit_cast(uint, f);
    u += 0x7FFFu + ((u >> 16) & 1u);
    return (ushort)(u >> 16);
}
__device__ __forceinline__ uint pack2(float a, float b) {
    uint ua = __builtin_bit_cast(uint, a), ub = __builtin_bit_cast(uint, b);
    ua += 0x7FFFu + ((ua >> 16) & 1u);
    ub += 0x7FFFu + ((ub >> 16) & 1u);
    return (ua >> 16) | (ub & 0xFFFF0000u);
}
__device__ __forceinline__ float blo(uint v) { return __builtin_bit_cast(float, v << 16); }
__device__ __forceinline__ float bhi(uint v) { return __builtin_bit_cast(float, v & 0xFFFF0000u); }

// ---------------------------------------------------------------------------
__global__ void cvt_x(const float* __restrict__ x, uint* __restrict__ xb2) {
    int t = blockIdx.x * blockDim.x + threadIdx.x;   // one float4 per thread
    if (t < NN * 16) {
        float4 v = reinterpret_cast<const float4*>(x)[t];
        uint2 o;
        o.x = pack2(v.x, v.y);
        o.y = pack2(v.z, v.w);
        reinterpret_cast<uint2*>(xb2)[t] = o;
    }
}

// W1t[f][k] (64x128): k<64 -> W1l[k][f], else W1r[k-64][f];  W2t (32x128) same.
__global__ void prep_w(const float* __restrict__ W1l, const float* __restrict__ W1r,
                       const float* __restrict__ W2l, const float* __restrict__ W2r,
                       ushort* __restrict__ W1t, ushort* __restrict__ W2t) {
    int t = blockIdx.x * blockDim.x + threadIdx.x;
    if (t < 64 * 128) {
        int f = t >> 7, k = t & 127;
        float v = (k < 64) ? W1l[k * 64 + f] : W1r[(k - 64) * 64 + f];
        W1t[t] = f2bf(v);
    } else if (t < 64 * 128 + 32 * 128) {
        int u = t - 64 * 128;
        int f = u >> 7, k = u & 127;
        float v = (k < 64) ? W2l[k * 32 + f] : W2r[(k - 64) * 32 + f];
        W2t[u] = f2bf(v);
    }
}

// ---------------------------------------------------------------------------
// Coarse histogram over buckets (dst >> 8), LDS-staged.
__global__ __launch_bounds__(512) void coarse_hist(const int* __restrict__ dst,
                                                   int* __restrict__ gh) {
    __shared__ int lh[NBK + 1];
    int tid = threadIdx.x;
    for (int i = tid; i < NBK + 1; i += 512) lh[i] = 0;
    __syncthreads();
    int base = blockIdx.x * CH;
#pragma unroll
    for (int k = 0; k < 16; ++k) {
        int e = base + tid + k * 512;
        if (e < NE) atomicAdd(&lh[dst[e] >> 8], 1);
    }
    __syncthreads();
    if (tid < NBK && lh[tid] > 0) atomicAdd(&gh[tid], lh[tid]);
}

// Exclusive scan of 391 bucket counts.
__global__ __launch_bounds__(512) void scan_buckets(const int* __restrict__ gh,
                                                    int* __restrict__ goff,
                                                    int* __restrict__ gcur) {
    __shared__ int s[512];
    int t = threadIdx.x;
    int v = (t < NBK) ? gh[t] : 0;
    s[t] = v;
    for (int d = 1; d < 512; d <<= 1) {
        __syncthreads();
        int add = (t >= d) ? s[t - d] : 0;
        __syncthreads();
        s[t] += add;
    }
    __syncthreads();
    int ex = s[t] - v;
    if (t < NBK) { goff[t] = ex; gcur[t] = ex; }
    if (t == NBK - 1) goff[NBK] = ex + v;   // == NE
}

// Binned scatter: reserve contiguous per-bucket runs, write src|(dstLocal<<24).
__global__ __launch_bounds__(512) void bin_edges(const int* __restrict__ src,
                                                 const int* __restrict__ dst,
                                                 int* __restrict__ gcur,
                                                 uint* __restrict__ binned) {
    __shared__ int lh[NBK + 1], lb[NBK + 1], lr[NBK + 1];
    int tid = threadIdx.x;
    for (int i = tid; i < NBK + 1; i += 512) { lh[i] = 0; lr[i] = 0; }
    __syncthreads();
    int base = blockIdx.x * CH;
#pragma unroll
    for (int k = 0; k < 16; ++k) {
        int e = base + tid + k * 512;
        if (e < NE) atomicAdd(&lh[dst[e] >> 8], 1);
    }
    __syncthreads();
    if (tid < NBK && lh[tid] > 0) lb[tid] = atomicAdd(&gcur[tid], lh[tid]);
    __syncthreads();
#pragma unroll
    for (int k = 0; k < 16; ++k) {
        int e = base + tid + k * 512;
        if (e < NE) {
            int d = dst[e];
            int bk = d >> 8;
            int r = atomicAdd(&lr[bk], 1);
            binned[lb[bk] + r] = (uint)src[e] | ((uint)(d & 255) << 24);
        }
    }
}

// Per-bucket LDS counting sort: bucket records -> fully dst-sorted ssrc + CSR off.
__global__ __launch_bounds__(256) void sort_bucket(const uint* __restrict__ binned,
                                                   const int* __restrict__ goff,
                                                   uint* __restrict__ ssrc,
                                                   int* __restrict__ off) {
    __shared__ uint recs[SCAP];
    __shared__ uint srt[SCAP];
    __shared__ int cnt[256], sc[256], cur[256];
    int b = blockIdx.x, t = threadIdx.x;
    int s = goff[b], e = goff[b + 1], n = e - s;
    cnt[t] = 0;
    __syncthreads();
    for (int i = t; i < n; i += 256) {
        uint r = binned[s + i];
        recs[i] = r;
        atomicAdd(&cnt[r >> 24], 1);
    }
    __syncthreads();
    int c = cnt[t];
    sc[t] = c;
    for (int d = 1; d < 256; d <<= 1) {
        __syncthreads();
        int add = (t >= d) ? sc[t - d] : 0;
        __syncthreads();
        sc[t] += add;
    }
    __syncthreads();
    int ex = sc[t] - c;
    cur[t] = ex;
    int gnode = b * 256 + t;
    if (gnode <= NN) off[gnode] = s + ex;   // covers off[NN] via bucket 390
    __syncthreads();
    for (int i = t; i < n; i += 256) {
        uint r = recs[i];
        int p = atomicAdd(&cur[r >> 24], 1);
        srt[p] = r & 0xFFFFFFu;
    }
    __syncthreads();
    for (int i = t; i < n; i += 256) ssrc[s + i] = srt[i];
}

// ---------------------------------------------------------------------------
// Gather-mean: 8 lanes per node, uint4 (16B) per lane, unroll 4
// -> 32 rows in flight per wave, zero cross-lane reduction.
__global__ __launch_bounds__(256) void gmean(const uint4* __restrict__ rows,
                                             const int* __restrict__ off,
                                             const uint* __restrict__ ssrc,
                                             uint4* __restrict__ mout) {
    int g = threadIdx.x >> 3;            // group 0..31
    int l = threadIdx.x & 7;             // lane in group
    int node = blockIdx.x * 32 + g;      // NN % 32 == 0 (100000 = 32*3125)
    int beg = off[node], end = off[node + 1];
    float a0 = 0.f, a1 = 0.f, a2 = 0.f, a3 = 0.f;
    float a4 = 0.f, a5 = 0.f, a6 = 0.f, a7 = 0.f;
    int i = beg;
    for (; i + 3 < end; i += 4) {
        int j0 = ssrc[i], j1 = ssrc[i + 1], j2 = ssrc[i + 2], j3 = ssrc[i + 3];
        uint4 v0 = rows[(size_t)j0 * 8 + l];
        uint4 v1 = rows[(size_t)j1 * 8 + l];
        uint4 v2 = rows[(size_t)j2 * 8 + l];
        uint4 v3 = rows[(size_t)j3 * 8 + l];
        a0 += blo(v0.x); a1 += bhi(v0.x); a2 += blo(v0.y); a3 += bhi(v0.y);
        a4 += blo(v0.z); a5 += bhi(v0.z); a6 += blo(v0.w); a7 += bhi(v0.w);
        a0 += blo(v1.x); a1 += bhi(v1.x); a2 += blo(v1.y); a3 += bhi(v1.y);
        a4 += blo(v1.z); a5 += bhi(v1.z); a6 += blo(v1.w); a7 += bhi(v1.w);
        a0 += blo(v2.x); a1 += bhi(v2.x); a2 += blo(v2.y); a3 += bhi(v2.y);
        a4 += blo(v2.z); a5 += bhi(v2.z); a6 += blo(v2.w); a7 += bhi(v2.w);
        a0 += blo(v3.x); a1 += bhi(v3.x); a2 += blo(v3.y); a3 += bhi(v3.y);
        a4 += blo(v3.z); a5 += bhi(v3.z); a6 += blo(v3.w); a7 += bhi(v3.w);
    }
    for (; i < end; ++i) {
        uint4 v = rows[(size_t)ssrc[i] * 8 + l];
        a0 += blo(v.x); a1 += bhi(v.x); a2 += blo(v.y); a3 += bhi(v.y);
        a4 += blo(v.z); a5 += bhi(v.z); a6 += blo(v.w); a7 += bhi(v.w);
    }
    float inv = 1.f / fmaxf((float)(end - beg), 1.f);
    uint4 o;
    o.x = pack2(a0 * inv, a1 * inv);
    o.y = pack2(a2 * inv, a3 * inv);
    o.z = pack2(a4 * inv, a5 * inv);
    o.w = pack2(a6 * inv, a7 * inv);
    mout[(size_t)node * 8 + l] = o;
}

// ---------------------------------------------------------------------------
// Layer 1 MFMA: hb = relu(l2norm([mean|x] @ W1t^T + b1)), bf16 out.
// C layout: col = lane&15, row = (lane>>4)*4 + reg  [m89-verified].
__global__ __launch_bounds__(256) void layer1_mfma(
    const ushort* __restrict__ mb, const ushort* __restrict__ xb,
    const ushort* __restrict__ Wt, const float* __restrict__ bias,
    ushort* __restrict__ hb) {
    int w = threadIdx.x >> 6, l = threadIdx.x & 63;
    int r = l & 15, q = l >> 4;
    int node0 = blockIdx.x * 64 + w * 16;
    int arow = node0 + r;
    if (arow >= NN) arow = NN - 1;      // clamp; invalid rows never stored
    const ushort* am = mb + (size_t)arow * 64 + q * 8;
    const ushort* ax = xb + (size_t)arow * 64 + q * 8;
    bf16x8 afr[4];
    afr[0] = *reinterpret_cast<const bf16x8*>(am);
    afr[1] = *reinterpret_cast<const bf16x8*>(am + 32);
    afr[2] = *reinterpret_cast<const bf16x8*>(ax);
    afr[3] = *reinterpret_cast<const bf16x8*>(ax + 32);

    f32x4 c0 = {0.f, 0.f, 0.f, 0.f}, c1 = c0, c2 = c0, c3 = c0;
    const ushort* wp = Wt + (size_t)r * 128 + q * 8;
#pragma unroll
    for (int ks = 0; ks < 4; ++ks) {
        const ushort* wk = wp + ks * 32;
        bf16x8 b0 = *reinterpret_cast<const bf16x8*>(wk);
        bf16x8 b1 = *reinterpret_cast<const bf16x8*>(wk + 16 * 128);
        bf16x8 b2 = *reinterpret_cast<const bf16x8*>(wk + 32 * 128);
        bf16x8 b3 = *reinterpret_cast<const bf16x8*>(wk + 48 * 128);
        c0 = __builtin_amdgcn_mfma_f32_16x16x32_bf16(afr[ks], b0, c0, 0, 0, 0);
        c1 = __builtin_amdgcn_mfma_f32_16x16x32_bf16(afr[ks], b1, c1, 0, 0, 0);
        c2 = __builtin_amdgcn_mfma_f32_16x16x32_bf16(afr[ks], b2, c2, 0, 0, 0);
        c3 = __builtin_amdgcn_mfma_f32_16x16x32_bf16(afr[ks], b3, c3, 0, 0, 0);
    }
    float bb0 = bias[r], bb1 = bias[16 + r], bb2 = bias[32 + r], bb3 = bias[48 + r];
#pragma unroll
    for (int reg = 0; reg < 4; ++reg) {
        c0[reg] += bb0; c1[reg] += bb1; c2[reg] += bb2; c3[reg] += bb3;
    }
    float sc[4];
#pragma unroll
    for (int reg = 0; reg < 4; ++reg) {
        float s = c0[reg] * c0[reg] + c1[reg] * c1[reg] +
                  c2[reg] * c2[reg] + c3[reg] * c3[reg];
        s += __shfl_xor(s, 1, 64);
        s += __shfl_xor(s, 2, 64);
        s += __shfl_xor(s, 4, 64);
        s += __shfl_xor(s, 8, 64);
        sc[reg] = 1.f / fmaxf(sqrtf(s), 1e-12f);
    }
#pragma unroll
    for (int reg = 0; reg < 4; ++reg) {
        int grow = node0 + q * 4 + reg;
        if (grow < NN) {
            ushort* hp = hb + (size_t)grow * 64 + r;
            hp[0]  = f2bf(fmaxf(c0[reg] * sc[reg], 0.f));
            hp[16] = f2bf(fmaxf(c1[reg] * sc[reg], 0.f));
            hp[32] = f2bf(fmaxf(c2[reg] * sc[reg], 0.f));
            hp[48] = f2bf(fmaxf(c3[reg] * sc[reg], 0.f));
        }
    }
}

// Layer 2 MFMA: out = l2norm([mean2|h] @ W2t^T + b2), fp32 out, 32 feats.
__global__ __launch_bounds__(256) void layer2_mfma(
    const ushort* __restrict__ mb, const ushort* __restrict__ hbuf,
    const ushort* __restrict__ Wt, const float* __restrict__ bias,
    float* __restrict__ out) {
    int w = threadIdx.x >> 6, l = threadIdx.x & 63;
    int r = l & 15, q = l >> 4;
    int node0 = blockIdx.x * 64 + w * 16;
    int arow = node0 + r;
    if (arow >= NN) arow = NN - 1;
    const ushort* am = mb + (size_t)arow * 64 + q * 8;
    const ushort* ax = hbuf + (size_t)arow * 64 + q * 8;
    bf16x8 afr[4];
    afr[0] = *reinterpret_cast<const bf16x8*>(am);
    afr[1] = *reinterpret_cast<const bf16x8*>(am + 32);
    afr[2] = *reinterpret_cast<const bf16x8*>(ax);
    afr[3] = *reinterpret_cast<const bf16x8*>(ax + 32);

    f32x4 c0 = {0.f, 0.f, 0.f, 0.f}, c1 = c0;
    const ushort* wp = Wt + (size_t)r * 128 + q * 8;
#pragma unroll
    for (int ks = 0; ks < 4; ++ks) {
        const ushort* wk = wp + ks * 32;
        bf16x8 b0 = *reinterpret_cast<const bf16x8*>(wk);
        bf16x8 b1 = *reinterpret_cast<const bf16x8*>(wk + 16 * 128);
        c0 = __builtin_amdgcn_mfma_f32_16x16x32_bf16(afr[ks], b0, c0, 0, 0, 0);
        c1 = __builtin_amdgcn_mfma_f32_16x16x32_bf16(afr[ks], b1, c1, 0, 0, 0);
    }
    float bb0 = bias[r], bb1 = bias[16 + r];
#pragma unroll
    for (int reg = 0; reg < 4; ++reg) { c0[reg] += bb0; c1[reg] += bb1; }
    float sc[4];
#pragma unroll
    for (int reg = 0; reg < 4; ++reg) {
        float s = c0[reg] * c0[reg] + c1[reg] * c1[reg];
        s += __shfl_xor(s, 1, 64);
        s += __shfl_xor(s, 2, 64);
        s += __shfl_xor(s, 4, 64);
        s += __shfl_xor(s, 8, 64);
        sc[reg] = 1.f / fmaxf(sqrtf(s), 1e-12f);
    }
#pragma unroll
    for (int reg = 0; reg < 4; ++reg) {
        int grow = node0 + q * 4 + reg;
        if (grow < NN) {
            float* op = out + (size_t)grow * 32 + r;
            op[0]  = c0[reg] * sc[reg];
            op[16] = c1[reg] * sc[reg];
        }
    }
}

// ---------------------------------------------------------------------------
extern "C" void kernel_launch(void* const* d_in, const int* in_sizes, int n_in,
                              void* d_out, int out_size, void* d_ws, size_t ws_size,
                              hipStream_t stream) {
    const float* x   = (const float*)d_in[0];
    const int*   ei  = (const int*)d_in[1];
    const int*   src = ei;            // edge_index[0]
    const int*   dst = ei + NE;       // edge_index[1]
    const float* W1l = (const float*)d_in[2];
    const float* b1  = (const float*)d_in[3];
    const float* W1r = (const float*)d_in[4];
    const float* W2l = (const float*)d_in[5];
    const float* b2  = (const float*)d_in[6];
    const float* W2r = (const float*)d_in[7];
    float* out = (float*)d_out;

    // ws: xb | mb | hb (bf16 N*64) | W1t | W2t | gh | goff | gcur | off | binned | ssrc
    ushort* xb   = (ushort*)d_ws;
    ushort* mb   = xb + (size_t)NN * 64;
    ushort* hb   = mb + (size_t)NN * 64;
    ushort* W1t  = hb + (size_t)NN * 64;
    ushort* W2t  = W1t + 64 * 128;
    int*    gh   = (int*)(W2t + 32 * 128);
    int*    goff = gh + NBK + 1;
    int*    gcur = goff + NBK + 1;
    int*    off  = gcur + NBK + 1;
    uint*   binn = (uint*)(off + NN + 1);
    uint*   ssrc = binn + NE;

    hipMemsetAsync(gh, 0, (NBK + 1) * sizeof(int), stream);

    cvt_x       <<<(NN * 16 + 255) / 256, 256, 0, stream>>>(x, (uint*)xb);
    prep_w      <<<48, 256, 0, stream>>>(W1l, W1r, W2l, W2r, W1t, W2t);
    coarse_hist <<<NCB, 512, 0, stream>>>(dst, gh);
    scan_buckets<<<1, 512, 0, stream>>>(gh, goff, gcur);
    bin_edges   <<<NCB, 512, 0, stream>>>(src, dst, gcur, binn);
    sort_bucket <<<NBK, 256, 0, stream>>>(binn, goff, ssrc, off);

    gmean      <<<NN / 32, 256, 0, stream>>>((const uint4*)xb, off, ssrc, (uint4*)mb);
    layer1_mfma<<<(NN + 63) / 64, 256, 0, stream>>>(mb, xb, W1t, b1, hb);
    gmean      <<<NN / 32, 256, 0, stream>>>((const uint4*)hb, off, ssrc, (uint4*)mb);
    layer2_mfma<<<(NN + 63) / 64, 256, 0, stream>>>(mb, hb, W2t, b2, out);
}

// Round 6
// 128.340 us; speedup vs baseline: 7.3683x; 1.0057x over previous
//
#include <hip/hip_runtime.h>

#define NN 100000
#define NE 1000000
#define NBK 391          // coarse buckets of 256 nodes
#define CH 8192          // edges per binning block
#define NCB ((NE + CH - 1) / CH)   // 123
#define SCAP 4096        // per-bucket sort capacity (avg 2560, sigma ~51)

typedef __attribute__((ext_vector_type(8))) short bf16x8;
typedef __attribute__((ext_vector_type(4))) float f32x4;

// ---------------------------------------------------------------------------
// bf16 helpers (RNE)
__device__ __forceinline__ ushort f2bf(float f) {
    uint u = __builtin_bit_cast(uint, f);
    u += 0x7FFFu + ((u >> 16) & 1u);
    return (ushort)(u >> 16);
}
__device__ __forceinline__ uint pack2(float a, float b) {
    uint ua = __builtin_bit_cast(uint, a), ub = __builtin_bit_cast(uint, b);
    ua += 0x7FFFu + ((ua >> 16) & 1u);
    ub += 0x7FFFu + ((ub >> 16) & 1u);
    return (ua >> 16) | (ub & 0xFFFF0000u);
}
__device__ __forceinline__ float blo(uint v) { return __builtin_bit_cast(float, v << 16); }
__device__ __forceinline__ float bhi(uint v) { return __builtin_bit_cast(float, v & 0xFFFF0000u); }

// ---------------------------------------------------------------------------
// Fused prep: x fp32 -> bf16, and weights -> transposed bf16 [Fout][128]
// (k<64 -> Wl[k][f], else Wr[k-64][f]).
__global__ void prep_all(const float* __restrict__ x, uint* __restrict__ xb2,
                         const float* __restrict__ W1l, const float* __restrict__ W1r,
                         const float* __restrict__ W2l, const float* __restrict__ W2r,
                         ushort* __restrict__ W1t, ushort* __restrict__ W2t) {
    int t = blockIdx.x * blockDim.x + threadIdx.x;
    if (t < NN * 16) {                       // one float4 -> uint2 per thread
        float4 v = reinterpret_cast<const float4*>(x)[t];
        uint2 o;
        o.x = pack2(v.x, v.y);
        o.y = pack2(v.z, v.w);
        reinterpret_cast<uint2*>(xb2)[t] = o;
    } else {
        int u = t - NN * 16;
        if (u < 64 * 128) {
            int f = u >> 7, k = u & 127;
            float v = (k < 64) ? W1l[k * 64 + f] : W1r[(k - 64) * 64 + f];
            W1t[u] = f2bf(v);
        } else if (u < 64 * 128 + 32 * 128) {
            int p = u - 64 * 128;
            int f = p >> 7, k = p & 127;
            float v = (k < 64) ? W2l[k * 32 + f] : W2r[(k - 64) * 32 + f];
            W2t[p] = f2bf(v);
        }
    }
}

// ---------------------------------------------------------------------------
// Coarse histogram over buckets (dst >> 8), LDS-staged.
__global__ __launch_bounds__(512) void coarse_hist(const int* __restrict__ dst,
                                                   int* __restrict__ gh) {
    __shared__ int lh[NBK + 1];
    int tid = threadIdx.x;
    for (int i = tid; i < NBK + 1; i += 512) lh[i] = 0;
    __syncthreads();
    int base = blockIdx.x * CH;
#pragma unroll
    for (int k = 0; k < 16; ++k) {
        int e = base + tid + k * 512;
        if (e < NE) atomicAdd(&lh[dst[e] >> 8], 1);
    }
    __syncthreads();
    if (tid < NBK && lh[tid] > 0) atomicAdd(&gh[tid], lh[tid]);
}

// Exclusive scan of 391 bucket counts.
__global__ __launch_bounds__(512) void scan_buckets(const int* __restrict__ gh,
                                                    int* __restrict__ goff,
                                                    int* __restrict__ gcur) {
    __shared__ int s[512];
    int t = threadIdx.x;
    int v = (t < NBK) ? gh[t] : 0;
    s[t] = v;
    for (int d = 1; d < 512; d <<= 1) {
        __syncthreads();
        int add = (t >= d) ? s[t - d] : 0;
        __syncthreads();
        s[t] += add;
    }
    __syncthreads();
    int ex = s[t] - v;
    if (t < NBK) { goff[t] = ex; gcur[t] = ex; }
    if (t == NBK - 1) goff[NBK] = ex + v;   // == NE
}

// Binned scatter: reserve contiguous per-bucket runs, write src|(dstLocal<<24).
__global__ __launch_bounds__(512) void bin_edges(const int* __restrict__ src,
                                                 const int* __restrict__ dst,
                                                 int* __restrict__ gcur,
                                                 uint* __restrict__ binned) {
    __shared__ int lh[NBK + 1], lb[NBK + 1], lr[NBK + 1];
    int tid = threadIdx.x;
    for (int i = tid; i < NBK + 1; i += 512) { lh[i] = 0; lr[i] = 0; }
    __syncthreads();
    int base = blockIdx.x * CH;
#pragma unroll
    for (int k = 0; k < 16; ++k) {
        int e = base + tid + k * 512;
        if (e < NE) atomicAdd(&lh[dst[e] >> 8], 1);
    }
    __syncthreads();
    if (tid < NBK && lh[tid] > 0) lb[tid] = atomicAdd(&gcur[tid], lh[tid]);
    __syncthreads();
#pragma unroll
    for (int k = 0; k < 16; ++k) {
        int e = base + tid + k * 512;
        if (e < NE) {
            int d = dst[e];
            int bk = d >> 8;
            int r = atomicAdd(&lr[bk], 1);
            binned[lb[bk] + r] = (uint)src[e] | ((uint)(d & 255) << 24);
        }
    }
}

// Per-bucket LDS counting sort: bucket records -> fully dst-sorted ssrc + CSR off.
__global__ __launch_bounds__(256) void sort_bucket(const uint* __restrict__ binned,
                                                   const int* __restrict__ goff,
                                                   uint* __restrict__ ssrc,
                                                   int* __restrict__ off) {
    __shared__ uint recs[SCAP];
    __shared__ uint srt[SCAP];
    __shared__ int cnt[256], sc[256], cur[256];
    int b = blockIdx.x, t = threadIdx.x;
    int s = goff[b], e = goff[b + 1], n = e - s;
    cnt[t] = 0;
    __syncthreads();
    for (int i = t; i < n; i += 256) {
        uint r = binned[s + i];
        recs[i] = r;
        atomicAdd(&cnt[r >> 24], 1);
    }
    __syncthreads();
    int c = cnt[t];
    sc[t] = c;
    for (int d = 1; d < 256; d <<= 1) {
        __syncthreads();
        int add = (t >= d) ? sc[t - d] : 0;
        __syncthreads();
        sc[t] += add;
    }
    __syncthreads();
    int ex = sc[t] - c;
    cur[t] = ex;
    int gnode = b * 256 + t;
    if (gnode <= NN) off[gnode] = s + ex;   // covers off[NN] via bucket 390
    __syncthreads();
    for (int i = t; i < n; i += 256) {
        uint r = recs[i];
        int p = atomicAdd(&cur[r >> 24], 1);
        srt[p] = r & 0xFFFFFFu;
    }
    __syncthreads();
    for (int i = t; i < n; i += 256) ssrc[s + i] = srt[i];
}

// ---------------------------------------------------------------------------
// Fused gather-mean + MFMA layer 1.
// Thread (r=lane&15, q=lane>>4) IS both the gatherer and the MFMA A-fragment
// holder for node node0+r, feats [q*8..q*8+7] and [32+q*8..+7]: it accumulates
// the neighbor mean for exactly those 16 features in registers (2x16B loads
// per neighbor, 2-edge unroll = 4 loads in flight), rounds to bf16, and feeds
// MFMA directly. No LDS, no mb round-trip.
// C layout: col(lane&15)=feature r, row(lane>>4)*4+reg = node  [m89-verified].
__global__ __launch_bounds__(256) void layer1_fused(
    const uint4* __restrict__ xb4, const ushort* __restrict__ xb,
    const int* __restrict__ off, const uint* __restrict__ ssrc,
    const ushort* __restrict__ Wt, const float* __restrict__ bias,
    ushort* __restrict__ hb) {
    int w = threadIdx.x >> 6, l = threadIdx.x & 63;
    int r = l & 15, q = l >> 4;
    int node0 = blockIdx.x * 64 + w * 16;
    int node = node0 + r;
    int beg = 0, end = 0;
    if (node < NN) { beg = off[node]; end = off[node + 1]; }
    float a0=0.f,a1=0.f,a2=0.f,a3=0.f,a4=0.f,a5=0.f,a6=0.f,a7=0.f;
    float b0=0.f,b1=0.f,b2=0.f,b3=0.f,b4=0.f,b5=0.f,b6=0.f,b7=0.f;
    int i = beg;
    for (; i + 1 < end; i += 2) {
        uint j0 = ssrc[i], j1 = ssrc[i + 1];
        uint4 u0 = xb4[(size_t)j0 * 8 + q];
        uint4 v0 = xb4[(size_t)j0 * 8 + q + 4];
        uint4 u1 = xb4[(size_t)j1 * 8 + q];
        uint4 v1 = xb4[(size_t)j1 * 8 + q + 4];
        a0 += blo(u0.x); a1 += bhi(u0.x); a2 += blo(u0.y); a3 += bhi(u0.y);
        a4 += blo(u0.z); a5 += bhi(u0.z); a6 += blo(u0.w); a7 += bhi(u0.w);
        b0 += blo(v0.x); b1 += bhi(v0.x); b2 += blo(v0.y); b3 += bhi(v0.y);
        b4 += blo(v0.z); b5 += bhi(v0.z); b6 += blo(v0.w); b7 += bhi(v0.w);
        a0 += blo(u1.x); a1 += bhi(u1.x); a2 += blo(u1.y); a3 += bhi(u1.y);
        a4 += blo(u1.z); a5 += bhi(u1.z); a6 += blo(u1.w); a7 += bhi(u1.w);
        b0 += blo(v1.x); b1 += bhi(v1.x); b2 += blo(v1.y); b3 += bhi(v1.y);
        b4 += blo(v1.z); b5 += bhi(v1.z); b6 += blo(v1.w); b7 += bhi(v1.w);
    }
    if (i < end) {
        uint j0 = ssrc[i];
        uint4 u0 = xb4[(size_t)j0 * 8 + q];
        uint4 v0 = xb4[(size_t)j0 * 8 + q + 4];
        a0 += blo(u0.x); a1 += bhi(u0.x); a2 += blo(u0.y); a3 += bhi(u0.y);
        a4 += blo(u0.z); a5 += bhi(u0.z); a6 += blo(u0.w); a7 += bhi(u0.w);
        b0 += blo(v0.x); b1 += bhi(v0.x); b2 += blo(v0.y); b3 += bhi(v0.y);
        b4 += blo(v0.z); b5 += bhi(v0.z); b6 += blo(v0.w); b7 += bhi(v0.w);
    }
    float inv = 1.f / fmaxf((float)(end - beg), 1.f);
    uint4 mu, mv;
    mu.x = pack2(a0 * inv, a1 * inv); mu.y = pack2(a2 * inv, a3 * inv);
    mu.z = pack2(a4 * inv, a5 * inv); mu.w = pack2(a6 * inv, a7 * inv);
    mv.x = pack2(b0 * inv, b1 * inv); mv.y = pack2(b2 * inv, b3 * inv);
    mv.z = pack2(b4 * inv, b5 * inv); mv.w = pack2(b6 * inv, b7 * inv);
    bf16x8 afr0 = __builtin_bit_cast(bf16x8, mu);
    bf16x8 afr1 = __builtin_bit_cast(bf16x8, mv);
    int arow = (node < NN) ? node : NN - 1;
    const ushort* ax = xb + (size_t)arow * 64 + q * 8;
    bf16x8 afr2 = *reinterpret_cast<const bf16x8*>(ax);
    bf16x8 afr3 = *reinterpret_cast<const bf16x8*>(ax + 32);

    f32x4 c0 = {0.f, 0.f, 0.f, 0.f}, c1 = c0, c2 = c0, c3 = c0;
    const ushort* wp = Wt + (size_t)r * 128 + q * 8;
#pragma unroll
    for (int ks = 0; ks < 4; ++ks) {
        const ushort* wk = wp + ks * 32;
        bf16x8 w0 = *reinterpret_cast<const bf16x8*>(wk);
        bf16x8 w1 = *reinterpret_cast<const bf16x8*>(wk + 16 * 128);
        bf16x8 w2 = *reinterpret_cast<const bf16x8*>(wk + 32 * 128);
        bf16x8 w3 = *reinterpret_cast<const bf16x8*>(wk + 48 * 128);
        bf16x8 af = (ks == 0) ? afr0 : (ks == 1) ? afr1 : (ks == 2) ? afr2 : afr3;
        c0 = __builtin_amdgcn_mfma_f32_16x16x32_bf16(af, w0, c0, 0, 0, 0);
        c1 = __builtin_amdgcn_mfma_f32_16x16x32_bf16(af, w1, c1, 0, 0, 0);
        c2 = __builtin_amdgcn_mfma_f32_16x16x32_bf16(af, w2, c2, 0, 0, 0);
        c3 = __builtin_amdgcn_mfma_f32_16x16x32_bf16(af, w3, c3, 0, 0, 0);
    }
    float bb0 = bias[r], bb1 = bias[16 + r], bb2 = bias[32 + r], bb3 = bias[48 + r];
#pragma unroll
    for (int reg = 0; reg < 4; ++reg) {
        c0[reg] += bb0; c1[reg] += bb1; c2[reg] += bb2; c3[reg] += bb3;
    }
#pragma unroll
    for (int reg = 0; reg < 4; ++reg) {
        float s = c0[reg] * c0[reg] + c1[reg] * c1[reg] +
                  c2[reg] * c2[reg] + c3[reg] * c3[reg];
        s += __shfl_xor(s, 1, 64);
        s += __shfl_xor(s, 2, 64);
        s += __shfl_xor(s, 4, 64);
        s += __shfl_xor(s, 8, 64);
        float scl = 1.f / fmaxf(sqrtf(s), 1e-12f);
        int grow = node0 + q * 4 + reg;
        if (grow < NN) {
            ushort* hp = hb + (size_t)grow * 64 + r;
            hp[0]  = f2bf(fmaxf(c0[reg] * scl, 0.f));
            hp[16] = f2bf(fmaxf(c1[reg] * scl, 0.f));
            hp[32] = f2bf(fmaxf(c2[reg] * scl, 0.f));
            hp[48] = f2bf(fmaxf(c3[reg] * scl, 0.f));
        }
    }
}

// Fused gather-mean + MFMA layer 2 (32 output feats, fp32 out).
__global__ __launch_bounds__(256) void layer2_fused(
    const uint4* __restrict__ hb4, const ushort* __restrict__ hbuf,
    const int* __restrict__ off, const uint* __restrict__ ssrc,
    const ushort* __restrict__ Wt, const float* __restrict__ bias,
    float* __restrict__ out) {
    int w = threadIdx.x >> 6, l = threadIdx.x & 63;
    int r = l & 15, q = l >> 4;
    int node0 = blockIdx.x * 64 + w * 16;
    int node = node0 + r;
    int beg = 0, end = 0;
    if (node < NN) { beg = off[node]; end = off[node + 1]; }
    float a0=0.f,a1=0.f,a2=0.f,a3=0.f,a4=0.f,a5=0.f,a6=0.f,a7=0.f;
    float b0=0.f,b1=0.f,b2=0.f,b3=0.f,b4=0.f,b5=0.f,b6=0.f,b7=0.f;
    int i = beg;
    for (; i + 1 < end; i += 2) {
        uint j0 = ssrc[i], j1 = ssrc[i + 1];
        uint4 u0 = hb4[(size_t)j0 * 8 + q];
        uint4 v0 = hb4[(size_t)j0 * 8 + q + 4];
        uint4 u1 = hb4[(size_t)j1 * 8 + q];
        uint4 v1 = hb4[(size_t)j1 * 8 + q + 4];
        a0 += blo(u0.x); a1 += bhi(u0.x); a2 += blo(u0.y); a3 += bhi(u0.y);
        a4 += blo(u0.z); a5 += bhi(u0.z); a6 += blo(u0.w); a7 += bhi(u0.w);
        b0 += blo(v0.x); b1 += bhi(v0.x); b2 += blo(v0.y); b3 += bhi(v0.y);
        b4 += blo(v0.z); b5 += bhi(v0.z); b6 += blo(v0.w); b7 += bhi(v0.w);
        a0 += blo(u1.x); a1 += bhi(u1.x); a2 += blo(u1.y); a3 += bhi(u1.y);
        a4 += blo(u1.z); a5 += bhi(u1.z); a6 += blo(u1.w); a7 += bhi(u1.w);
        b0 += blo(v1.x); b1 += bhi(v1.x); b2 += blo(v1.y); b3 += bhi(v1.y);
        b4 += blo(v1.z); b5 += bhi(v1.z); b6 += blo(v1.w); b7 += bhi(v1.w);
    }
    if (i < end) {
        uint j0 = ssrc[i];
        uint4 u0 = hb4[(size_t)j0 * 8 + q];
        uint4 v0 = hb4[(size_t)j0 * 8 + q + 4];
        a0 += blo(u0.x); a1 += bhi(u0.x); a2 += blo(u0.y); a3 += bhi(u0.y);
        a4 += blo(u0.z); a5 += bhi(u0.z); a6 += blo(u0.w); a7 += bhi(u0.w);
        b0 += blo(v0.x); b1 += bhi(v0.x); b2 += blo(v0.y); b3 += bhi(v0.y);
        b4 += blo(v0.z); b5 += bhi(v0.z); b6 += blo(v0.w); b7 += bhi(v0.w);
    }
    float inv = 1.f / fmaxf((float)(end - beg), 1.f);
    uint4 mu, mv;
    mu.x = pack2(a0 * inv, a1 * inv); mu.y = pack2(a2 * inv, a3 * inv);
    mu.z = pack2(a4 * inv, a5 * inv); mu.w = pack2(a6 * inv, a7 * inv);
    mv.x = pack2(b0 * inv, b1 * inv); mv.y = pack2(b2 * inv, b3 * inv);
    mv.z = pack2(b4 * inv, b5 * inv); mv.w = pack2(b6 * inv, b7 * inv);
    bf16x8 afr0 = __builtin_bit_cast(bf16x8, mu);
    bf16x8 afr1 = __builtin_bit_cast(bf16x8, mv);
    int arow = (node < NN) ? node : NN - 1;
    const ushort* ax = hbuf + (size_t)arow * 64 + q * 8;
    bf16x8 afr2 = *reinterpret_cast<const bf16x8*>(ax);
    bf16x8 afr3 = *reinterpret_cast<const bf16x8*>(ax + 32);

    f32x4 c0 = {0.f, 0.f, 0.f, 0.f}, c1 = c0;
    const ushort* wp = Wt + (size_t)r * 128 + q * 8;
#pragma unroll
    for (int ks = 0; ks < 4; ++ks) {
        const ushort* wk = wp + ks * 32;
        bf16x8 w0 = *reinterpret_cast<const bf16x8*>(wk);
        bf16x8 w1 = *reinterpret_cast<const bf16x8*>(wk + 16 * 128);
        bf16x8 af = (ks == 0) ? afr0 : (ks == 1) ? afr1 : (ks == 2) ? afr2 : afr3;
        c0 = __builtin_amdgcn_mfma_f32_16x16x32_bf16(af, w0, c0, 0, 0, 0);
        c1 = __builtin_amdgcn_mfma_f32_16x16x32_bf16(af, w1, c1, 0, 0, 0);
    }
    float bb0 = bias[r], bb1 = bias[16 + r];
#pragma unroll
    for (int reg = 0; reg < 4; ++reg) { c0[reg] += bb0; c1[reg] += bb1; }
#pragma unroll
    for (int reg = 0; reg < 4; ++reg) {
        float s = c0[reg] * c0[reg] + c1[reg] * c1[reg];
        s += __shfl_xor(s, 1, 64);
        s += __shfl_xor(s, 2, 64);
        s += __shfl_xor(s, 4, 64);
        s += __shfl_xor(s, 8, 64);
        float scl = 1.f / fmaxf(sqrtf(s), 1e-12f);
        int grow = node0 + q * 4 + reg;
        if (grow < NN) {
            float* op = out + (size_t)grow * 32 + r;
            op[0]  = c0[reg] * scl;
            op[16] = c1[reg] * scl;
        }
    }
}

// ---------------------------------------------------------------------------
extern "C" void kernel_launch(void* const* d_in, const int* in_sizes, int n_in,
                              void* d_out, int out_size, void* d_ws, size_t ws_size,
                              hipStream_t stream) {
    const float* x   = (const float*)d_in[0];
    const int*   ei  = (const int*)d_in[1];
    const int*   src = ei;            // edge_index[0]
    const int*   dst = ei + NE;       // edge_index[1]
    const float* W1l = (const float*)d_in[2];
    const float* b1  = (const float*)d_in[3];
    const float* W1r = (const float*)d_in[4];
    const float* W2l = (const float*)d_in[5];
    const float* b2  = (const float*)d_in[6];
    const float* W2r = (const float*)d_in[7];
    float* out = (float*)d_out;

    // ws: xb | hb (bf16 N*64) | W1t | W2t | gh | goff | gcur | off | binned | ssrc
    ushort* xb   = (ushort*)d_ws;
    ushort* hb   = xb + (size_t)NN * 64;
    ushort* W1t  = hb + (size_t)NN * 64;
    ushort* W2t  = W1t + 64 * 128;
    int*    gh   = (int*)(W2t + 32 * 128);
    int*    goff = gh + NBK + 1;
    int*    gcur = goff + NBK + 1;
    int*    off  = gcur + NBK + 1;
    uint*   binn = (uint*)(off + NN + 1);
    uint*   ssrc = binn + NE;

    hipMemsetAsync(gh, 0, (NBK + 1) * sizeof(int), stream);

    prep_all    <<<(NN * 16 + 12288 + 255) / 256, 256, 0, stream>>>(
                    x, (uint*)xb, W1l, W1r, W2l, W2r, W1t, W2t);
    coarse_hist <<<NCB, 512, 0, stream>>>(dst, gh);
    scan_buckets<<<1, 512, 0, stream>>>(gh, goff, gcur);
    bin_edges   <<<NCB, 512, 0, stream>>>(src, dst, gcur, binn);
    sort_bucket <<<NBK, 256, 0, stream>>>(binn, goff, ssrc, off);

    layer1_fused<<<(NN + 63) / 64, 256, 0, stream>>>(
                    (const uint4*)xb, xb, off, ssrc, W1t, b1, hb);
    layer2_fused<<<(NN + 63) / 64, 256, 0, stream>>>(
                    (const uint4*)hb, hb, off, ssrc, W2t, b2, out);
}

// Round 7
// 114.181 us; speedup vs baseline: 8.2821x; 1.1240x over previous
//
#include <hip/hip_runtime.h>

#define NN 100000
#define NE 1000000
#define NBK 391          // coarse buckets of 256 nodes
#define CAP 3072         // fixed bucket capacity (mean 2560, sigma ~51: +10 sigma)
#define CH 8192          // edges per binning block
#define NCB ((NE + CH - 1) / CH)   // 123

typedef __attribute__((ext_vector_type(8))) short bf16x8;
typedef __attribute__((ext_vector_type(4))) float f32x4;

// ---------------------------------------------------------------------------
// bf16 helpers (RNE)
__device__ __forceinline__ ushort f2bf(float f) {
    uint u = __builtin_bit_cast(uint, f);
    u += 0x7FFFu + ((u >> 16) & 1u);
    return (ushort)(u >> 16);
}
__device__ __forceinline__ uint pack2(float a, float b) {
    uint ua = __builtin_bit_cast(uint, a), ub = __builtin_bit_cast(uint, b);
    ua += 0x7FFFu + ((ua >> 16) & 1u);
    ub += 0x7FFFu + ((ub >> 16) & 1u);
    return (ua >> 16) | (ub & 0xFFFF0000u);
}
__device__ __forceinline__ float blo(uint v) { return __builtin_bit_cast(float, v << 16); }
__device__ __forceinline__ float bhi(uint v) { return __builtin_bit_cast(float, v & 0xFFFF0000u); }

#define ACC8(u, v)                                                         \
    a0 += blo(u.x); a1 += bhi(u.x); a2 += blo(u.y); a3 += bhi(u.y);        \
    a4 += blo(u.z); a5 += bhi(u.z); a6 += blo(u.w); a7 += bhi(u.w);        \
    b0 += blo(v.x); b1 += bhi(v.x); b2 += blo(v.y); b3 += bhi(v.y);        \
    b4 += blo(v.z); b5 += bhi(v.z); b6 += blo(v.w); b7 += bhi(v.w);

// ---------------------------------------------------------------------------
// Fused prep: x fp32 -> bf16; weights -> transposed bf16 [Fout][128]
// (k<64 -> Wl[k][f] else Wr[k-64][f]); bucket cursors -> b*CAP.
__global__ void prep_all(const float* __restrict__ x, uint* __restrict__ xb2,
                         const float* __restrict__ W1l, const float* __restrict__ W1r,
                         const float* __restrict__ W2l, const float* __restrict__ W2r,
                         ushort* __restrict__ W1t, ushort* __restrict__ W2t,
                         int* __restrict__ gcur) {
    int t = blockIdx.x * blockDim.x + threadIdx.x;
    if (t < NN * 16) {                       // one float4 -> uint2 per thread
        float4 v = reinterpret_cast<const float4*>(x)[t];
        uint2 o;
        o.x = pack2(v.x, v.y);
        o.y = pack2(v.z, v.w);
        reinterpret_cast<uint2*>(xb2)[t] = o;
    } else {
        int u = t - NN * 16;
        if (u < 64 * 128) {
            int f = u >> 7, k = u & 127;
            float v = (k < 64) ? W1l[k * 64 + f] : W1r[(k - 64) * 64 + f];
            W1t[u] = f2bf(v);
        } else if (u < 64 * 128 + 32 * 128) {
            int p = u - 64 * 128;
            int f = p >> 7, k = p & 127;
            float v = (k < 64) ? W2l[k * 32 + f] : W2r[(k - 64) * 32 + f];
            W2t[p] = f2bf(v);
        } else if (u < 64 * 128 + 32 * 128 + NBK) {
            int b = u - 64 * 128 - 32 * 128;
            gcur[b] = b * CAP;
        }
    }
}

// ---------------------------------------------------------------------------
// Binned scatter into fixed-capacity buckets: LDS histogram, reserve a
// contiguous run per bucket via one global atomic, write src|(dstLocal<<24).
__global__ __launch_bounds__(512) void bin_edges(const int* __restrict__ src,
                                                 const int* __restrict__ dst,
                                                 int* __restrict__ gcur,
                                                 uint* __restrict__ binned) {
    __shared__ int lh[NBK + 1], lb[NBK + 1], lr[NBK + 1];
    int tid = threadIdx.x;
    for (int i = tid; i < NBK + 1; i += 512) { lh[i] = 0; lr[i] = 0; }
    __syncthreads();
    int base = blockIdx.x * CH;
#pragma unroll
    for (int k = 0; k < 16; ++k) {
        int e = base + tid + k * 512;
        if (e < NE) atomicAdd(&lh[dst[e] >> 8], 1);
    }
    __syncthreads();
    if (tid < NBK && lh[tid] > 0) lb[tid] = atomicAdd(&gcur[tid], lh[tid]);
    __syncthreads();
#pragma unroll
    for (int k = 0; k < 16; ++k) {
        int e = base + tid + k * 512;
        if (e < NE) {
            int d = dst[e];
            int bk = d >> 8;
            int r = atomicAdd(&lr[bk], 1);
            binned[lb[bk] + r] = (uint)src[e] | ((uint)(d & 255) << 24);
        }
    }
}

// Per-bucket LDS counting sort -> dst-sorted ssrc (gapped layout) + packed CSR:
// offp[node] = pos | (deg << 22).   pos < 391*3072 = 1.2M < 2^22; deg < 1024.
__global__ __launch_bounds__(256) void sort_bucket(const uint* __restrict__ binned,
                                                   const int* __restrict__ gcur,
                                                   uint* __restrict__ ssrc,
                                                   uint* __restrict__ offp) {
    __shared__ uint recs[CAP];
    __shared__ uint srt[CAP];
    __shared__ int cnt[256], sc[256], cur[256];
    int b = blockIdx.x, t = threadIdx.x;
    int s = b * CAP, n = gcur[b] - s;
    cnt[t] = 0;
    __syncthreads();
    for (int i = t; i < n; i += 256) {
        uint r = binned[s + i];
        recs[i] = r;
        atomicAdd(&cnt[r >> 24], 1);
    }
    __syncthreads();
    int c = cnt[t];
    sc[t] = c;
    for (int d = 1; d < 256; d <<= 1) {
        __syncthreads();
        int add = (t >= d) ? sc[t - d] : 0;
        __syncthreads();
        sc[t] += add;
    }
    __syncthreads();
    int ex = sc[t] - c;
    cur[t] = ex;
    int node = b * 256 + t;
    if (node < NN) offp[node] = (uint)(s + ex) | ((uint)c << 22);
    __syncthreads();
    for (int i = t; i < n; i += 256) {
        uint r = recs[i];
        int p = atomicAdd(&cur[r >> 24], 1);
        srt[p] = r & 0xFFFFFFu;
    }
    __syncthreads();
    for (int i = t; i < n; i += 256) ssrc[s + i] = srt[i];
}

// ---------------------------------------------------------------------------
// Fused gather-mean + MFMA layer 1. Thread (r=lane&15, q=lane>>4) gathers the
// 16-feature mean slice for node node0+r in registers (4-edge unroll = 8x16B
// row loads + 4 ssrc loads in flight), then feeds MFMA directly.
// C layout: col(lane&15)=feature, row=(lane>>4)*4+reg = node  [m89-verified].
__global__ __launch_bounds__(256) void layer1_fused(
    const uint4* __restrict__ xb4, const ushort* __restrict__ xb,
    const uint* __restrict__ offp, const uint* __restrict__ ssrc,
    const ushort* __restrict__ Wt, const float* __restrict__ bias,
    ushort* __restrict__ hb) {
    int w = threadIdx.x >> 6, l = threadIdx.x & 63;
    int r = l & 15, q = l >> 4;
    int node0 = blockIdx.x * 64 + w * 16;
    int node = node0 + r;
    int beg = 0, end = 0;
    if (node < NN) {
        uint p = offp[node];
        beg = (int)(p & 0x3FFFFFu);
        end = beg + (int)(p >> 22);
    }
    float a0=0.f,a1=0.f,a2=0.f,a3=0.f,a4=0.f,a5=0.f,a6=0.f,a7=0.f;
    float b0=0.f,b1=0.f,b2=0.f,b3=0.f,b4=0.f,b5=0.f,b6=0.f,b7=0.f;
    int i = beg;
    for (; i + 3 < end; i += 4) {
        uint j0 = ssrc[i], j1 = ssrc[i + 1], j2 = ssrc[i + 2], j3 = ssrc[i + 3];
        uint4 u0 = xb4[(size_t)j0 * 8 + q];
        uint4 v0 = xb4[(size_t)j0 * 8 + q + 4];
        uint4 u1 = xb4[(size_t)j1 * 8 + q];
        uint4 v1 = xb4[(size_t)j1 * 8 + q + 4];
        uint4 u2 = xb4[(size_t)j2 * 8 + q];
        uint4 v2 = xb4[(size_t)j2 * 8 + q + 4];
        uint4 u3 = xb4[(size_t)j3 * 8 + q];
        uint4 v3 = xb4[(size_t)j3 * 8 + q + 4];
        ACC8(u0, v0) ACC8(u1, v1) ACC8(u2, v2) ACC8(u3, v3)
    }
    for (; i < end; ++i) {
        uint j0 = ssrc[i];
        uint4 u0 = xb4[(size_t)j0 * 8 + q];
        uint4 v0 = xb4[(size_t)j0 * 8 + q + 4];
        ACC8(u0, v0)
    }
    float inv = 1.f / fmaxf((float)(end - beg), 1.f);
    uint4 mu, mv;
    mu.x = pack2(a0 * inv, a1 * inv); mu.y = pack2(a2 * inv, a3 * inv);
    mu.z = pack2(a4 * inv, a5 * inv); mu.w = pack2(a6 * inv, a7 * inv);
    mv.x = pack2(b0 * inv, b1 * inv); mv.y = pack2(b2 * inv, b3 * inv);
    mv.z = pack2(b4 * inv, b5 * inv); mv.w = pack2(b6 * inv, b7 * inv);
    bf16x8 afr0 = __builtin_bit_cast(bf16x8, mu);
    bf16x8 afr1 = __builtin_bit_cast(bf16x8, mv);
    int arow = (node < NN) ? node : NN - 1;
    const ushort* ax = xb + (size_t)arow * 64 + q * 8;
    bf16x8 afr2 = *reinterpret_cast<const bf16x8*>(ax);
    bf16x8 afr3 = *reinterpret_cast<const bf16x8*>(ax + 32);

    f32x4 c0 = {0.f, 0.f, 0.f, 0.f}, c1 = c0, c2 = c0, c3 = c0;
    const ushort* wp = Wt + (size_t)r * 128 + q * 8;
#pragma unroll
    for (int ks = 0; ks < 4; ++ks) {
        const ushort* wk = wp + ks * 32;
        bf16x8 w0 = *reinterpret_cast<const bf16x8*>(wk);
        bf16x8 w1 = *reinterpret_cast<const bf16x8*>(wk + 16 * 128);
        bf16x8 w2 = *reinterpret_cast<const bf16x8*>(wk + 32 * 128);
        bf16x8 w3 = *reinterpret_cast<const bf16x8*>(wk + 48 * 128);
        bf16x8 af = (ks == 0) ? afr0 : (ks == 1) ? afr1 : (ks == 2) ? afr2 : afr3;
        c0 = __builtin_amdgcn_mfma_f32_16x16x32_bf16(af, w0, c0, 0, 0, 0);
        c1 = __builtin_amdgcn_mfma_f32_16x16x32_bf16(af, w1, c1, 0, 0, 0);
        c2 = __builtin_amdgcn_mfma_f32_16x16x32_bf16(af, w2, c2, 0, 0, 0);
        c3 = __builtin_amdgcn_mfma_f32_16x16x32_bf16(af, w3, c3, 0, 0, 0);
    }
    float bb0 = bias[r], bb1 = bias[16 + r], bb2 = bias[32 + r], bb3 = bias[48 + r];
#pragma unroll
    for (int reg = 0; reg < 4; ++reg) {
        c0[reg] += bb0; c1[reg] += bb1; c2[reg] += bb2; c3[reg] += bb3;
    }
#pragma unroll
    for (int reg = 0; reg < 4; ++reg) {
        float s = c0[reg] * c0[reg] + c1[reg] * c1[reg] +
                  c2[reg] * c2[reg] + c3[reg] * c3[reg];
        s += __shfl_xor(s, 1, 64);
        s += __shfl_xor(s, 2, 64);
        s += __shfl_xor(s, 4, 64);
        s += __shfl_xor(s, 8, 64);
        float scl = 1.f / fmaxf(sqrtf(s), 1e-12f);
        int grow = node0 + q * 4 + reg;
        if (grow < NN) {
            ushort* hp = hb + (size_t)grow * 64 + r;
            hp[0]  = f2bf(fmaxf(c0[reg] * scl, 0.f));
            hp[16] = f2bf(fmaxf(c1[reg] * scl, 0.f));
            hp[32] = f2bf(fmaxf(c2[reg] * scl, 0.f));
            hp[48] = f2bf(fmaxf(c3[reg] * scl, 0.f));
        }
    }
}

// Fused gather-mean + MFMA layer 2 (32 output feats, fp32 out).
__global__ __launch_bounds__(256) void layer2_fused(
    const uint4* __restrict__ hb4, const ushort* __restrict__ hbuf,
    const uint* __restrict__ offp, const uint* __restrict__ ssrc,
    const ushort* __restrict__ Wt, const float* __restrict__ bias,
    float* __restrict__ out) {
    int w = threadIdx.x >> 6, l = threadIdx.x & 63;
    int r = l & 15, q = l >> 4;
    int node0 = blockIdx.x * 64 + w * 16;
    int node = node0 + r;
    int beg = 0, end = 0;
    if (node < NN) {
        uint p = offp[node];
        beg = (int)(p & 0x3FFFFFu);
        end = beg + (int)(p >> 22);
    }
    float a0=0.f,a1=0.f,a2=0.f,a3=0.f,a4=0.f,a5=0.f,a6=0.f,a7=0.f;
    float b0=0.f,b1=0.f,b2=0.f,b3=0.f,b4=0.f,b5=0.f,b6=0.f,b7=0.f;
    int i = beg;
    for (; i + 3 < end; i += 4) {
        uint j0 = ssrc[i], j1 = ssrc[i + 1], j2 = ssrc[i + 2], j3 = ssrc[i + 3];
        uint4 u0 = hb4[(size_t)j0 * 8 + q];
        uint4 v0 = hb4[(size_t)j0 * 8 + q + 4];
        uint4 u1 = hb4[(size_t)j1 * 8 + q];
        uint4 v1 = hb4[(size_t)j1 * 8 + q + 4];
        uint4 u2 = hb4[(size_t)j2 * 8 + q];
        uint4 v2 = hb4[(size_t)j2 * 8 + q + 4];
        uint4 u3 = hb4[(size_t)j3 * 8 + q];
        uint4 v3 = hb4[(size_t)j3 * 8 + q + 4];
        ACC8(u0, v0) ACC8(u1, v1) ACC8(u2, v2) ACC8(u3, v3)
    }
    for (; i < end; ++i) {
        uint j0 = ssrc[i];
        uint4 u0 = hb4[(size_t)j0 * 8 + q];
        uint4 v0 = hb4[(size_t)j0 * 8 + q + 4];
        ACC8(u0, v0)
    }
    float inv = 1.f / fmaxf((float)(end - beg), 1.f);
    uint4 mu, mv;
    mu.x = pack2(a0 * inv, a1 * inv); mu.y = pack2(a2 * inv, a3 * inv);
    mu.z = pack2(a4 * inv, a5 * inv); mu.w = pack2(a6 * inv, a7 * inv);
    mv.x = pack2(b0 * inv, b1 * inv); mv.y = pack2(b2 * inv, b3 * inv);
    mv.z = pack2(b4 * inv, b5 * inv); mv.w = pack2(b6 * inv, b7 * inv);
    bf16x8 afr0 = __builtin_bit_cast(bf16x8, mu);
    bf16x8 afr1 = __builtin_bit_cast(bf16x8, mv);
    int arow = (node < NN) ? node : NN - 1;
    const ushort* ax = hbuf + (size_t)arow * 64 + q * 8;
    bf16x8 afr2 = *reinterpret_cast<const bf16x8*>(ax);
    bf16x8 afr3 = *reinterpret_cast<const bf16x8*>(ax + 32);

    f32x4 c0 = {0.f, 0.f, 0.f, 0.f}, c1 = c0;
    const ushort* wp = Wt + (size_t)r * 128 + q * 8;
#pragma unroll
    for (int ks = 0; ks < 4; ++ks) {
        const ushort* wk = wp + ks * 32;
        bf16x8 w0 = *reinterpret_cast<const bf16x8*>(wk);
        bf16x8 w1 = *reinterpret_cast<const bf16x8*>(wk + 16 * 128);
        bf16x8 af = (ks == 0) ? afr0 : (ks == 1) ? afr1 : (ks == 2) ? afr2 : afr3;
        c0 = __builtin_amdgcn_mfma_f32_16x16x32_bf16(af, w0, c0, 0, 0, 0);
        c1 = __builtin_amdgcn_mfma_f32_16x16x32_bf16(af, w1, c1, 0, 0, 0);
    }
    float bb0 = bias[r], bb1 = bias[16 + r];
#pragma unroll
    for (int reg = 0; reg < 4; ++reg) { c0[reg] += bb0; c1[reg] += bb1; }
#pragma unroll
    for (int reg = 0; reg < 4; ++reg) {
        float s = c0[reg] * c0[reg] + c1[reg] * c1[reg];
        s += __shfl_xor(s, 1, 64);
        s += __shfl_xor(s, 2, 64);
        s += __shfl_xor(s, 4, 64);
        s += __shfl_xor(s, 8, 64);
        float scl = 1.f / fmaxf(sqrtf(s), 1e-12f);
        int grow = node0 + q * 4 + reg;
        if (grow < NN) {
            float* op = out + (size_t)grow * 32 + r;
            op[0]  = c0[reg] * scl;
            op[16] = c1[reg] * scl;
        }
    }
}

// ---------------------------------------------------------------------------
extern "C" void kernel_launch(void* const* d_in, const int* in_sizes, int n_in,
                              void* d_out, int out_size, void* d_ws, size_t ws_size,
                              hipStream_t stream) {
    const float* x   = (const float*)d_in[0];
    const int*   ei  = (const int*)d_in[1];
    const int*   src = ei;            // edge_index[0]
    const int*   dst = ei + NE;       // edge_index[1]
    const float* W1l = (const float*)d_in[2];
    const float* b1  = (const float*)d_in[3];
    const float* W1r = (const float*)d_in[4];
    const float* W2l = (const float*)d_in[5];
    const float* b2  = (const float*)d_in[6];
    const float* W2r = (const float*)d_in[7];
    float* out = (float*)d_out;

    // ws: xb | hb (bf16 N*64) | W1t | W2t | gcur | offp | binned | ssrc
    ushort* xb   = (ushort*)d_ws;
    ushort* hb   = xb + (size_t)NN * 64;
    ushort* W1t  = hb + (size_t)NN * 64;
    ushort* W2t  = W1t + 64 * 128;
    int*    gcur = (int*)(W2t + 32 * 128);
    uint*   offp = (uint*)(gcur + NBK + 1);
    uint*   binn = offp + NN;
    uint*   ssrc = binn + (size_t)NBK * CAP;

    prep_all    <<<(NN * 16 + 12288 + NBK + 255) / 256, 256, 0, stream>>>(
                    x, (uint*)xb, W1l, W1r, W2l, W2r, W1t, W2t, gcur);
    bin_edges   <<<NCB, 512, 0, stream>>>(src, dst, gcur, binn);
    sort_bucket <<<NBK, 256, 0, stream>>>(binn, gcur, ssrc, offp);

    layer1_fused<<<(NN + 63) / 64, 256, 0, stream>>>(
                    (const uint4*)xb, xb, offp, ssrc, W1t, b1, hb);
    layer2_fused<<<(NN + 63) / 64, 256, 0, stream>>>(
                    (const uint4*)hb, hb, offp, ssrc, W2t, b2, out);
}